// Round 4
// baseline (436.647 us; speedup 1.0000x reference)
//
#include <hip/hip_runtime.h>

typedef __bf16 bf16;
typedef __attribute__((ext_vector_type(8))) __bf16 v8bf;
typedef __attribute__((ext_vector_type(4))) __bf16 v4bf;
typedef __attribute__((ext_vector_type(4))) float f32x4;
typedef __attribute__((ext_vector_type(16))) float f32x16;

static_assert(sizeof(v8bf) == 16, "v8bf must be 16B");

#define MFMA16(a, b, c) __builtin_amdgcn_mfma_f32_16x16x32_bf16((a), (b), (c), 0, 0, 0)
#define MFMA32(a, b, c) __builtin_amdgcn_mfma_f32_32x32x16_bf16((a), (b), (c), 0, 0, 0)

__device__ __forceinline__ void async_lds16(const bf16* g, bf16* l) {
  __builtin_amdgcn_global_load_lds(
      (__attribute__((address_space(1))) void*)(g),
      (__attribute__((address_space(3))) void*)(l), 16, 0, 0);
}

// ---------------------------------------------------------------------------
// Kernel 0: convert q,k,v and both weight matrices fp32 -> bf16.
// ---------------------------------------------------------------------------
__global__ __launch_bounds__(256) void cvt_kernel(
    const float* __restrict__ q, const float* __restrict__ k,
    const float* __restrict__ v, const float* __restrict__ wi,
    const float* __restrict__ wo, bf16* __restrict__ xq, bf16* __restrict__ xk,
    bf16* __restrict__ xv, bf16* __restrict__ Wb, bf16* __restrict__ Wob) {
  int idx = blockIdx.x * 256 + threadIdx.x;  // 0..7340031
  const float4* src;
  v4bf* dst;
  int off;
  if (idx < 2097152)      { src = (const float4*)q;  dst = (v4bf*)xq;  off = idx; }
  else if (idx < 4194304) { src = (const float4*)k;  dst = (v4bf*)xk;  off = idx - 2097152; }
  else if (idx < 6291456) { src = (const float4*)v;  dst = (v4bf*)xv;  off = idx - 4194304; }
  else if (idx < 7077888) { src = (const float4*)wi; dst = (v4bf*)Wb;  off = idx - 6291456; }
  else                    { src = (const float4*)wo; dst = (v4bf*)Wob; off = idx - 7077888; }
  float4 f = src[off];
  v4bf b;
  b[0] = (bf16)f.x; b[1] = (bf16)f.y; b[2] = (bf16)f.z; b[3] = (bf16)f.w;
  dst[off] = b;
}

// ---------------------------------------------------------------------------
// GEMM core v3: 32x32x16 MFMA, BM=BN=256 BK=64, 256 thr / 4 waves (2x2),
// per-wave output 128x128 (acc[4][4] f32x16 = 256 VGPR), 1 wave/SIMD.
// Rationale (R3 post-mortem): all schedules at 64x64/wave tie at ~76us ->
// traffic-bound, not latency-bound. 128x128/wave halves LDS bytes/FLOP
// ((Mw+Nw)/(Mw*Nw): 32 -> 64 FLOP per LDS-read-elem); 32x32 MFMA is 17%
// cheaper per MAC than 2x 16x16x32. One barrier + one vmcnt(0) per K-tile
// (stage of t+1 issued at t's start, drained ~4 fat phases later); no
// intra-tile sync; compiler schedules ds_read under MFMA.
// Swizzle: granule slot s of row r holds k-granule s ^ swz(r),
// swz(r) = (r ^ (r>>3)) & 7  -> <=2-way within any 16-lane chunk for
// 32-row b128 frag reads (rows r, r+8, r+16, r+24 get distinct slots).
// Staged via pre-swizzled global source (linear LDS dest, m104-safe).
// ---------------------------------------------------------------------------
#define TSZ (256 * 64)  // one A (or B) buffer: 32 KB

#define STAGE32(BUF, KO)                                                      \
  do {                                                                        \
    bf16* Ad = Asmb + (BUF) * TSZ + wdst;                                     \
    bf16* Bd = Bsmb + (BUF) * TSZ + wdst;                                     \
    _Pragma("unroll") for (int i = 0; i < 8; ++i)                             \
        async_lds16(Xa + (size_t)sOff[i] + (KO), Ad + i * 2048);              \
    _Pragma("unroll") for (int i = 0; i < 8; ++i)                             \
        async_lds16(Wbase + (size_t)sOff[i] + (KO), Bd + i * 2048);           \
  } while (0)

// A-frag read: lane holds A[row = base+ (l&31)][k = (l>>5)*8 + j].
// elem addr = row*64 + slot*8, slot = (ks*2)^kh^swz(row); with
// row = wm*128 + MH*64 + fm*32 + (l&31): swz folds to swzbase ^ (fm*4),
// so slot*8 = (ks*16) ^ (fm*32) ^ plA8  (XOR distributes over <<3).
#define LOADA(BUF, MH)                                                        \
  _Pragma("unroll") for (int ks = 0; ks < 4; ++ks) {                          \
    aR[0][ks] = *(const v8bf*)&Asmb[(BUF) * TSZ + aBase + (MH) * 4096 +       \
                                    ((ks * 16) ^ plA8)];                      \
    aR[1][ks] = *(const v8bf*)&Asmb[(BUF) * TSZ + aBase + (MH) * 4096 +       \
                                    2048 + ((ks * 16) ^ 32 ^ plA8)];          \
  }

#define LOADB(BUF, NH)                                                        \
  _Pragma("unroll") for (int ks = 0; ks < 4; ++ks) {                          \
    bR[NH][0][ks] = *(const v8bf*)&Bsmb[(BUF) * TSZ + bBase + (NH) * 4096 +   \
                                        ((ks * 16) ^ plA8)];                  \
    bR[NH][1][ks] = *(const v8bf*)&Bsmb[(BUF) * TSZ + bBase + (NH) * 4096 +   \
                                        2048 + ((ks * 16) ^ 32 ^ plA8)];      \
  }

#define MFMAQ(MH, NH)                                                         \
  _Pragma("unroll") for (int ks = 0; ks < 4; ++ks) {                          \
    acc[(MH)*2+0][(NH)*2+0] =                                                 \
        MFMA32(aR[0][ks], bR[NH][0][ks], acc[(MH)*2+0][(NH)*2+0]);            \
    acc[(MH)*2+0][(NH)*2+1] =                                                 \
        MFMA32(aR[0][ks], bR[NH][1][ks], acc[(MH)*2+0][(NH)*2+1]);            \
    acc[(MH)*2+1][(NH)*2+0] =                                                 \
        MFMA32(aR[1][ks], bR[NH][0][ks], acc[(MH)*2+1][(NH)*2+0]);            \
    acc[(MH)*2+1][(NH)*2+1] =                                                 \
        MFMA32(aR[1][ks], bR[NH][1][ks], acc[(MH)*2+1][(NH)*2+1]);            \
  }

// Quadrant order (0,0)(0,1)(1,1)(1,0): A reloaded once, both B banks held.
// Per tile: 32 ds_read_b128/wave (minimum) + 16 gload_lds/thread staging.
#define TILE32(BUF, STAGE_STMT)                                               \
  do {                                                                        \
    STAGE_STMT;                                                               \
    LOADA(BUF, 0)                                                             \
    LOADB(BUF, 0)                                                             \
    MFMAQ(0, 0)                                                               \
    LOADB(BUF, 1)                                                             \
    MFMAQ(0, 1)                                                               \
    LOADA(BUF, 1)                                                             \
    MFMAQ(1, 1)                                                               \
    MFMAQ(1, 0)                                                               \
    asm volatile("s_waitcnt vmcnt(0)" ::: "memory");                          \
    __builtin_amdgcn_s_barrier();                                             \
  } while (0)

#define GEMM32_PRELUDE()                                                      \
  const int tid = threadIdx.x;                                                \
  const int w = tid >> 6, l = tid & 63;                                       \
  const int wm = w >> 1, wn = w & 1;                                          \
  const int c31 = l & 31, kh = l >> 5;                                        \
  const int plA8 = ((kh ^ c31 ^ (c31 >> 3)) & 7) * 8;                         \
  const int aBase = (wm * 128 + c31) * 64;                                    \
  const int bBase = (wn * 128 + c31) * 64;                                    \
  const int wdst = (tid & ~63) * 8;                                           \
  int sOff[8];                                                                \
  _Pragma("unroll") for (int i = 0; i < 8; ++i) {                             \
    const int ch = i * 256 + tid;                                             \
    const int rw = ch >> 3;                                                   \
    sOff[i] = rw * 1024 + (((ch & 7) ^ ((rw ^ (rw >> 3)) & 7)) * 8);          \
  }                                                                           \
  v8bf aR[2][4], bR[2][2][4];                                                 \
  f32x16 acc[4][4] = {};                                                      \
  STAGE32(0, 0);                                                              \
  asm volatile("s_waitcnt vmcnt(0)" ::: "memory");                            \
  __builtin_amdgcn_s_barrier();                                               \
  _Pragma("unroll 1") for (int t = 0; t < 16; t += 2) {                       \
    TILE32(0, STAGE32(1, (t + 1) * 64));                                      \
    TILE32(1, if (t < 14) STAGE32(0, (t + 2) * 64));                          \
  }

// ---------------------------------------------------------------------------
// Kernel 1: QKV projection. Grid 384 = 12 B-groups x 32 consecutive m-blocks:
// consecutive blocks share the B-tile (L2 broadcast, XCD-mapping-robust);
// same-m blocks sit 32 apart (same XCD under %8 round-robin -> X L2 reuse).
// ---------------------------------------------------------------------------
__global__ __launch_bounds__(256, 1) void qkv_proj_kernel(
    const bf16* __restrict__ xq, const bf16* __restrict__ xk,
    const bf16* __restrict__ xv, const bf16* __restrict__ Wb,
    const float* __restrict__ bias, bf16* __restrict__ oq,
    bf16* __restrict__ ok, bf16* __restrict__ ov) {
  __shared__ bf16 Asm2[2][TSZ];  // 64 KB
  __shared__ bf16 Bsm2[2][TSZ];  // 64 KB
  bf16* Asmb = &Asm2[0][0];
  bf16* Bsmb = &Bsm2[0][0];
  const int L = blockIdx.x;      // 0..383
  const int g = L >> 5;          // B-group 0..11
  const int c = g >> 2;
  const int n0 = (g & 3) * 256;
  const int m0 = (L & 31) * 256;
  const bf16* X = (c == 0) ? xq : (c == 1) ? xk : xv;
  bf16* outp = (c == 0) ? oq : (c == 1) ? ok : ov;
  const bf16* Xa = X + (size_t)m0 * 1024;
  const bf16* Wbase = Wb + ((size_t)(c * 1024 + n0)) * 1024;

  GEMM32_PRELUDE();

  // C/D 32x32: col = lane&31, row = (r&3) + 8*(r>>2) + 4*(lane>>5)
  const float scale = (c == 0) ? 0.125f : 1.0f;
#pragma unroll
  for (int mf = 0; mf < 4; ++mf)
#pragma unroll
    for (int nf = 0; nf < 4; ++nf) {
      const int n = n0 + wn * 128 + nf * 32 + c31;
      const float bn = bias[c * 1024 + n];
      const int hh = n >> 6, d = n & 63;
#pragma unroll
      for (int r = 0; r < 16; ++r) {
        const int m = m0 + wm * 128 + mf * 32 + (r & 3) + ((r >> 2) * 8) + kh * 4;
        const int t_ = m >> 3, b = m & 7;
        outp[((size_t)((b * 16 + hh) * 1024 + t_)) * 64 + d] =
            (bf16)((acc[mf][nf][r] + bn) * scale);
      }
    }
}

// ---------------------------------------------------------------------------
// Kernel 2: transpose V per head: [bh][t][d] -> [bh][d][t]
// ---------------------------------------------------------------------------
__global__ __launch_bounds__(256) void transpose_v_kernel(const bf16* __restrict__ vin,
                                                          bf16* __restrict__ vout) {
  __shared__ bf16 tile[64][72];
  const int bh = blockIdx.x;
  const int t0 = blockIdx.y * 64;
  const int tid = threadIdx.x;
  const int row = tid >> 2, cg = (tid & 3) * 16;
  const bf16* src = vin + ((size_t)bh * 1024 + t0 + row) * 64 + cg;
#pragma unroll
  for (int i = 0; i < 2; ++i) {
    v8bf x = *(const v8bf*)(src + i * 8);
#pragma unroll
    for (int jj = 0; jj < 8; ++jj) tile[row][cg + i * 8 + jj] = x[jj];
  }
  __syncthreads();
  const int d = tid >> 2, tg = (tid & 3) * 16;
  bf16* dst = vout + ((size_t)bh * 64 + d) * 1024 + t0 + tg;
  v8bf o0, o1;
#pragma unroll
  for (int i = 0; i < 8; ++i) o0[i] = tile[tg + i][d];
#pragma unroll
  for (int i = 0; i < 8; ++i) o1[i] = tile[tg + 8 + i][d];
  *(v8bf*)dst = o0;
  *(v8bf*)(dst + 8) = o1;
}

// ---------------------------------------------------------------------------
// Kernel 3: flash-style attention v3 — NO online softmax (scores bounded).
// ---------------------------------------------------------------------------
#define KSTR 72    // Ksm row stride: 64 data + 8 pad
#define VSTR 136   // Vsm/Psm row stride: 128 data + 8 pad

__global__ __launch_bounds__(256, 2) void attn_kernel(const bf16* __restrict__ qh,
                                                      const bf16* __restrict__ kh,
                                                      const bf16* __restrict__ vT,
                                                      bf16* __restrict__ attn_out) {
  __shared__ bf16 Ksm[128 * KSTR];    // 18432 B
  __shared__ bf16 Vsm[64 * VSTR];     // 17408 B
  __shared__ bf16 Psm[128 * VSTR];    // 34816 B
  const int L = blockIdx.x;  // 0..1023
  const int bh = (L & 7) * 16 + ((L >> 3) & 15);
  const int t0 = (L >> 7) * 128;
  const int tid = threadIdx.x;
  const int w = tid >> 6, l = tid & 63, quad = l >> 4, lr = l & 15;
  const int qr0 = t0 + w * 32;

  const bf16* khead = kh + (size_t)bh * 1024 * 64;
  const bf16* vhead = vT + (size_t)bh * 64 * 1024;

  const size_t qbase = ((size_t)bh * 1024 + qr0 + lr) * 64 + quad * 8;
  const v8bf bq00 = *(const v8bf*)(qh + qbase);
  const v8bf bq01 = *(const v8bf*)(qh + qbase + 32);
  const v8bf bq10 = *(const v8bf*)(qh + qbase + 1024);
  const v8bf bq11 = *(const v8bf*)(qh + qbase + 1024 + 32);

  const int krow = tid >> 1, kd = (tid & 1) * 32;
  const int vrow = tid >> 2, vk = (tid & 3) * 32;
  const bf16* kg = khead + (size_t)krow * 64 + kd;
  const bf16* vg = vhead + (size_t)vrow * 1024 + vk;
  bf16* Kw = &Ksm[krow * KSTR + kd];
  bf16* Vw = &Vsm[vrow * VSTR + vk];
  bf16* Pw = &Psm[w * 32 * VSTR];

  v8bf kst[4], vst[4];
#pragma unroll
  for (int i = 0; i < 4; ++i) kst[i] = *(const v8bf*)(kg + i * 8);
#pragma unroll
  for (int i = 0; i < 4; ++i) vst[i] = *(const v8bf*)(vg + i * 8);

  float rsum0 = 0.0f, rsum1 = 0.0f;
  f32x4 oacc0[4] = {}, oacc1[4] = {};

  for (int c = 0; c < 8; ++c) {
    __syncthreads();
#pragma unroll
    for (int i = 0; i < 4; ++i) *(v8bf*)(Kw + i * 8) = kst[i];
#pragma unroll
    for (int i = 0; i < 4; ++i) *(v8bf*)(Vw + i * 8) = vst[i];
    __syncthreads();
    if (c < 7) {
      const bf16* kg2 = kg + (size_t)(c + 1) * 128 * 64;
      const bf16* vg2 = vg + (c + 1) * 128;
#pragma unroll
      for (int i = 0; i < 4; ++i) kst[i] = *(const v8bf*)(kg2 + i * 8);
#pragma unroll
      for (int i = 0; i < 4; ++i) vst[i] = *(const v8bf*)(vg2 + i * 8);
    }

#pragma unroll
    for (int kt = 0; kt < 8; ++kt) {
      const v8bf ak0 = *(const v8bf*)&Ksm[(kt * 16 + lr) * KSTR + quad * 8];
      const v8bf ak1 = *(const v8bf*)&Ksm[(kt * 16 + lr) * KSTR + 32 + quad * 8];
      f32x4 a = {};
      a = MFMA16(ak0, bq00, a);
      a = MFMA16(ak1, bq01, a);
      f32x4 b = {};
      b = MFMA16(ak0, bq10, b);
      b = MFMA16(ak1, bq11, b);
      v4bf pb0, pb1;
#pragma unroll
      for (int j = 0; j < 4; ++j) {
        const float p0 = __expf(a[j]);
        const float p1 = __expf(b[j]);
        rsum0 += p0;
        rsum1 += p1;
        pb0[j] = (bf16)p0;
        pb1[j] = (bf16)p1;
      }
      *(v4bf*)(Pw + lr * VSTR + kt * 16 + quad * 4) = pb0;
      *(v4bf*)(Pw + (16 + lr) * VSTR + kt * 16 + quad * 4) = pb1;
    }

#pragma unroll
    for (int ks = 0; ks < 4; ++ks) {
      const v8bf pa0 = *(const v8bf*)(Pw + lr * VSTR + ks * 32 + quad * 8);
      const v8bf pa1 = *(const v8bf*)(Pw + (16 + lr) * VSTR + ks * 32 + quad * 8);
#pragma unroll
      for (int dt = 0; dt < 4; ++dt) {
        const v8bf vb = *(const v8bf*)&Vsm[(dt * 16 + lr) * VSTR + ks * 32 + quad * 8];
        oacc0[dt] = MFMA16(pa0, vb, oacc0[dt]);
        oacc1[dt] = MFMA16(pa1, vb, oacc1[dt]);
      }
    }
  }

  rsum0 += __shfl_xor(rsum0, 16);
  rsum0 += __shfl_xor(rsum0, 32);
  rsum1 += __shfl_xor(rsum1, 16);
  rsum1 += __shfl_xor(rsum1, 32);
  const float inv0 = 1.0f / rsum0;
  const float inv1 = 1.0f / rsum1;
  const int b = bh >> 4, h = bh & 15;
#pragma unroll
  for (int j = 0; j < 4; ++j) {
    const float i0 = __shfl(inv0, quad * 4 + j);
    const float i1 = __shfl(inv1, quad * 4 + j);
    const int t0j = qr0 + quad * 4 + j;
#pragma unroll
    for (int dt = 0; dt < 4; ++dt) {
      attn_out[((size_t)(t0j * 8 + b)) * 1024 + h * 64 + dt * 16 + lr] =
          (bf16)(oacc0[dt][j] * i0);
      attn_out[((size_t)((t0j + 16) * 8 + b)) * 1024 + h * 64 + dt * 16 + lr] =
          (bf16)(oacc1[dt][j] * i1);
    }
  }
}

// ---------------------------------------------------------------------------
// Kernel 4: out projection, same 32x32 core. Grid 128 = 4 n-groups x 32 m.
// ---------------------------------------------------------------------------
__global__ __launch_bounds__(256, 1) void out_proj_kernel(const bf16* __restrict__ A,
                                                          const bf16* __restrict__ Wob,
                                                          const float* __restrict__ bias,
                                                          float* __restrict__ out) {
  __shared__ bf16 Asm2[2][TSZ];
  __shared__ bf16 Bsm2[2][TSZ];
  bf16* Asmb = &Asm2[0][0];
  bf16* Bsmb = &Bsm2[0][0];
  const int L = blockIdx.x;  // 0..127
  const int n0 = (L >> 5) * 256;
  const int m0 = (L & 31) * 256;
  const bf16* Xa = A + (size_t)m0 * 1024;
  const bf16* Wbase = Wob + (size_t)n0 * 1024;

  GEMM32_PRELUDE();

#pragma unroll
  for (int mf = 0; mf < 4; ++mf)
#pragma unroll
    for (int nf = 0; nf < 4; ++nf) {
      const int n = n0 + wn * 128 + nf * 32 + c31;
      const float bn = bias[n];
#pragma unroll
      for (int r = 0; r < 16; ++r) {
        const int m = m0 + wm * 128 + mf * 32 + (r & 3) + ((r >> 2) * 8) + kh * 4;
        out[(size_t)m * 1024 + n] = acc[mf][nf][r] + bn;
      }
    }
}

// ---------------------------------------------------------------------------
// Launcher. Workspace (72 MB) + d_out as early scratch.
// ---------------------------------------------------------------------------
extern "C" void kernel_launch(void* const* d_in, const int* in_sizes, int n_in,
                              void* d_out, int out_size, void* d_ws, size_t ws_size,
                              hipStream_t stream) {
  const float* q  = (const float*)d_in[0];
  const float* k  = (const float*)d_in[1];
  const float* v  = (const float*)d_in[2];
  const float* wi = (const float*)d_in[3];
  const float* bi = (const float*)d_in[4];
  const float* wo = (const float*)d_in[5];
  const float* bo = (const float*)d_in[6];
  float* out = (float*)d_out;
  char* ws = (char*)d_ws;
  const size_t MB = (size_t)1 << 20;
  bf16* Wb     = (bf16*)(ws + 0 * MB);
  bf16* Wob    = (bf16*)(ws + 6 * MB);
  bf16* wsq    = (bf16*)(ws + 8 * MB);
  bf16* wsk    = (bf16*)(ws + 24 * MB);
  bf16* wsv    = (bf16*)(ws + 40 * MB);
  bf16* xv     = (bf16*)(ws + 56 * MB);
  bf16* wsvT   = (bf16*)(ws + 56 * MB);
  bf16* xq     = (bf16*)d_out;
  bf16* xk     = (bf16*)((char*)d_out + 16 * MB);
  bf16* wsattn = wsv;

  cvt_kernel<<<dim3(28672), dim3(256), 0, stream>>>(q, k, v, wi, wo, xq, xk, xv, Wb, Wob);
  qkv_proj_kernel<<<dim3(384), dim3(256), 0, stream>>>(xq, xk, xv, Wb, bi, wsq, wsk, wsv);
  transpose_v_kernel<<<dim3(128, 16), dim3(256), 0, stream>>>(wsv, wsvT);
  attn_kernel<<<dim3(1024), dim3(256), 0, stream>>>(wsq, wsk, wsvT, wsattn);
  out_proj_kernel<<<dim3(128), dim3(256), 0, stream>>>(wsattn, Wob, bo, out);
}

// Round 5
// 299.575 us; speedup vs baseline: 1.4576x; 1.4576x over previous
//
#include <hip/hip_runtime.h>

typedef __bf16 bf16;
typedef __attribute__((ext_vector_type(8))) __bf16 v8bf;
typedef __attribute__((ext_vector_type(4))) __bf16 v4bf;
typedef __attribute__((ext_vector_type(4))) float f32x4;

static_assert(sizeof(v8bf) == 16, "v8bf must be 16B");

#define MFMA16(a, b, c) __builtin_amdgcn_mfma_f32_16x16x32_bf16((a), (b), (c), 0, 0, 0)

__device__ __forceinline__ void async_lds16(const bf16* g, bf16* l) {
  __builtin_amdgcn_global_load_lds(
      (__attribute__((address_space(1))) void*)(g),
      (__attribute__((address_space(3))) void*)(l), 16, 0, 0);
}

// ---------------------------------------------------------------------------
// Kernel 0: convert q,k,v and both weight matrices fp32 -> bf16.
// ---------------------------------------------------------------------------
__global__ __launch_bounds__(256) void cvt_kernel(
    const float* __restrict__ q, const float* __restrict__ k,
    const float* __restrict__ v, const float* __restrict__ wi,
    const float* __restrict__ wo, bf16* __restrict__ xq, bf16* __restrict__ xk,
    bf16* __restrict__ xv, bf16* __restrict__ Wb, bf16* __restrict__ Wob) {
  int idx = blockIdx.x * 256 + threadIdx.x;  // 0..7340031
  const float4* src;
  v4bf* dst;
  int off;
  if (idx < 2097152)      { src = (const float4*)q;  dst = (v4bf*)xq;  off = idx; }
  else if (idx < 4194304) { src = (const float4*)k;  dst = (v4bf*)xk;  off = idx - 2097152; }
  else if (idx < 6291456) { src = (const float4*)v;  dst = (v4bf*)xv;  off = idx - 4194304; }
  else if (idx < 7077888) { src = (const float4*)wi; dst = (v4bf*)Wb;  off = idx - 6291456; }
  else                    { src = (const float4*)wo; dst = (v4bf*)Wob; off = idx - 7077888; }
  float4 f = src[off];
  v4bf b;
  b[0] = (bf16)f.x; b[1] = (bf16)f.y; b[2] = (bf16)f.z; b[3] = (bf16)f.w;
  dst[off] = b;
}

// ---------------------------------------------------------------------------
// GEMM core v4 (m201 geometry): BM=BN=256 BK=64, 512 thr / 8 waves (2M x 4N),
// per-wave 128x64 output (acc[8][4] f32x4 = 128 VGPR). 2 LDS buffers, 128 KB.
// Per K-step t = 4 phases (g-half x k-half); per phase: 4-8 ds_read_b128,
// 2 global_load_lds chunk-stages, 1 barrier, 16 MFMA (setprio-wrapped).
// Chunks (1 load/thread, 64 rows x 64 k): A q0..q3 rows (q*64..), B same.
// Stage plan (window W_t reads step t, buf=t&1):
//   P1: A q1,q3 (step t+1 -> buf^1)   [slots last read P4(W_{t-1})]
//   P2: B q2,q3 (t+1)                 [B last read P2(W_{t-1})]
//   P3: A q0,q2 (step t+2 -> buf)     [A-g0 last read P2(W_t)]
//   P4: B q0,q1 (t+2), vmcnt(4)       [forces ALL of step t+1: 12-in-flight]
// Leads to force-point: 3-6 phases; overwrite >=1 barrier after last read.
// Swizzle (R0/R1-proven, 0 conflicts): LDS row r slot s holds k-granule
// s^(r&7) via pre-swizzled global source; reader slot ((kh*4+quad)^(lr&7)).
// LDS-read floor 2312cy < MFMA floor 2484cy per K-step per CU (feasible,
// unlike the 64x64/wave geometry: 1506 > 1241 -> was LDS-bound).
// ---------------------------------------------------------------------------
#define TSZ 16384  // elems per buffer per matrix (256*64)

#define STG_A(OB, CQ, KO)                                                     \
  async_lds16(Xa + (size_t)((CQ) * 65536 + (KO)) + srcoff,                    \
              Asmb + (OB) * TSZ + (CQ) * 4096 + dstW)
#define STG_B(OB, CQ, KO)                                                     \
  async_lds16(Wbase + (size_t)((CQ) * 65536 + (KO)) + srcoff,                 \
              Bsmb + (OB) * TSZ + (CQ) * 4096 + dstW)

#define WIN(BUF, OBUF, T)                                                     \
  do {                                                                        \
    const int t1 = (T) + 1, t2 = (T) + 2;                                     \
    const int ko1 = t1 * 64, ko2 = t2 * 64;                                   \
    v8bf a0[4], a1[4], bk0[4], bk1[4];                                        \
    /* P1: (g0,k0) */                                                         \
    _Pragma("unroll") for (int f = 0; f < 4; ++f)                             \
        a0[f] = *(const v8bf*)&Asmb[(BUF) * TSZ + aoff + f * 1024 + rs0];     \
    _Pragma("unroll") for (int nf = 0; nf < 4; ++nf)                          \
        bk0[nf] = *(const v8bf*)&Bsmb[(BUF) * TSZ + boff + nf * 1024 + rs0];  \
    if (t1 < 16) { STG_A(OBUF, 1, ko1); STG_A(OBUF, 3, ko1); }                \
    __builtin_amdgcn_s_barrier();                                             \
    __builtin_amdgcn_s_setprio(1);                                            \
    _Pragma("unroll") for (int f = 0; f < 4; ++f)                             \
        _Pragma("unroll") for (int nf = 0; nf < 4; ++nf)                      \
            acc[f][nf] = MFMA16(a0[f], bk0[nf], acc[f][nf]);                  \
    __builtin_amdgcn_s_setprio(0);                                            \
    /* P2: (g0,k1) */                                                         \
    _Pragma("unroll") for (int f = 0; f < 4; ++f)                             \
        a1[f] = *(const v8bf*)&Asmb[(BUF) * TSZ + aoff + f * 1024 + rs1];     \
    _Pragma("unroll") for (int nf = 0; nf < 4; ++nf)                          \
        bk1[nf] = *(const v8bf*)&Bsmb[(BUF) * TSZ + boff + nf * 1024 + rs1];  \
    if (t1 < 16) { STG_B(OBUF, 2, ko1); STG_B(OBUF, 3, ko1); }                \
    __builtin_amdgcn_s_barrier();                                             \
    __builtin_amdgcn_s_setprio(1);                                            \
    _Pragma("unroll") for (int f = 0; f < 4; ++f)                             \
        _Pragma("unroll") for (int nf = 0; nf < 4; ++nf)                      \
            acc[f][nf] = MFMA16(a1[f], bk1[nf], acc[f][nf]);                  \
    __builtin_amdgcn_s_setprio(0);                                            \
    /* P3: (g1,k0) */                                                         \
    _Pragma("unroll") for (int f = 0; f < 4; ++f)                             \
        a0[f] =                                                               \
            *(const v8bf*)&Asmb[(BUF) * TSZ + aoff + 4096 + f * 1024 + rs0];  \
    if (t2 < 16) { STG_A(BUF, 0, ko2); STG_A(BUF, 2, ko2); }                  \
    __builtin_amdgcn_s_barrier();                                             \
    __builtin_amdgcn_s_setprio(1);                                            \
    _Pragma("unroll") for (int f = 0; f < 4; ++f)                             \
        _Pragma("unroll") for (int nf = 0; nf < 4; ++nf)                      \
            acc[4 + f][nf] = MFMA16(a0[f], bk0[nf], acc[4 + f][nf]);          \
    __builtin_amdgcn_s_setprio(0);                                            \
    /* P4: (g1,k1) */                                                         \
    _Pragma("unroll") for (int f = 0; f < 4; ++f)                             \
        a1[f] =                                                               \
            *(const v8bf*)&Asmb[(BUF) * TSZ + aoff + 4096 + f * 1024 + rs1];  \
    if (t2 < 16) { STG_B(BUF, 0, ko2); STG_B(BUF, 1, ko2); }                  \
    if ((T) < 14) asm volatile("s_waitcnt vmcnt(4)" ::: "memory");            \
    else          asm volatile("s_waitcnt vmcnt(0)" ::: "memory");            \
    __builtin_amdgcn_s_barrier();                                             \
    __builtin_amdgcn_s_setprio(1);                                            \
    _Pragma("unroll") for (int f = 0; f < 4; ++f)                             \
        _Pragma("unroll") for (int nf = 0; nf < 4; ++nf)                      \
            acc[4 + f][nf] = MFMA16(a1[f], bk1[nf], acc[4 + f][nf]);          \
    __builtin_amdgcn_s_setprio(0);                                            \
  } while (0)

#define GEMM_PRELUDE()                                                        \
  const int tid = threadIdx.x;                                                \
  const int w = tid >> 6, l = tid & 63, quad = l >> 4, lr = l & 15;           \
  const int wmg = w >> 2, wng = w & 3;                                        \
  const int rbase = tid >> 3;                                                 \
  const int srcoff = rbase * 1024 + (((tid & 7) ^ (rbase & 7)) * 8);          \
  const int dstW = (tid & ~63) * 8;                                           \
  const int rs0 = ((quad) ^ (lr & 7)) * 8;                                    \
  const int rs1 = ((4 + quad) ^ (lr & 7)) * 8;                                \
  const int aoff = (wmg * 128 + lr) * 64;                                     \
  const int boff = (wng * 64 + lr) * 64;                                      \
  f32x4 acc[8][4] = {};                                                       \
  /* prologue: step0 all 8 chunks -> buf0; step1 first-4 (Aq0,Aq2,Bq0,Bq1) */ \
  _Pragma("unroll") for (int cq = 0; cq < 4; ++cq) {                          \
    STG_A(0, cq, 0);                                                          \
    STG_B(0, cq, 0);                                                          \
  }                                                                           \
  STG_A(1, 0, 64);                                                            \
  STG_A(1, 2, 64);                                                            \
  STG_B(1, 0, 64);                                                            \
  STG_B(1, 1, 64);                                                            \
  asm volatile("s_waitcnt vmcnt(4)" ::: "memory");                            \
  __builtin_amdgcn_s_barrier();                                               \
  _Pragma("unroll 1") for (int ip = 0; ip < 8; ++ip) {                        \
    WIN(0, 1, 2 * ip);                                                        \
    WIN(1, 0, 2 * ip + 1);                                                    \
  }

// ---------------------------------------------------------------------------
// Kernel 1: QKV projection. Grid 384 = 12 B-groups (c,nq) x 32 m-blocks:
// 32 consecutive blocks share one 512 KB B-panel (L2-resident); A streams
// once (L3 covers all inputs). M=8192 N=1024x3 K=1024.
// ---------------------------------------------------------------------------
__global__ __launch_bounds__(512, 2) void qkv_proj_kernel(
    const bf16* __restrict__ xq, const bf16* __restrict__ xk,
    const bf16* __restrict__ xv, const bf16* __restrict__ Wb,
    const float* __restrict__ bias, bf16* __restrict__ oq,
    bf16* __restrict__ ok, bf16* __restrict__ ov) {
  __shared__ bf16 Asm2[2][TSZ];  // 64 KB
  __shared__ bf16 Bsm2[2][TSZ];  // 64 KB
  bf16* Asmb = &Asm2[0][0];
  bf16* Bsmb = &Bsm2[0][0];
  const int L = blockIdx.x;   // 0..383
  const int g = L >> 5;       // 0..11
  const int c = g >> 2;
  const int n0 = (g & 3) * 256;
  const int m0 = (L & 31) * 256;
  const bf16* X = (c == 0) ? xq : (c == 1) ? xk : xv;
  bf16* outp = (c == 0) ? oq : (c == 1) ? ok : ov;
  const bf16* Xa = X + (size_t)m0 * 1024;
  const bf16* Wbase = Wb + ((size_t)(c * 1024 + n0)) * 1024;

  GEMM_PRELUDE();

  const float scale = (c == 0) ? 0.125f : 1.0f;
#pragma unroll
  for (int mf = 0; mf < 8; ++mf)
#pragma unroll
    for (int nf = 0; nf < 4; ++nf) {
      const int n = n0 + wng * 64 + nf * 16 + lr;
      const float bn = bias[c * 1024 + n];
      const int hh = n >> 6, d = n & 63;
#pragma unroll
      for (int j = 0; j < 4; ++j) {
        const int m = m0 + wmg * 128 + (mf >> 2) * 64 + (mf & 3) * 16 +
                      quad * 4 + j;
        const int t_ = m >> 3, b = m & 7;
        outp[((size_t)((b * 16 + hh) * 1024 + t_)) * 64 + d] =
            (bf16)((acc[mf][nf][j] + bn) * scale);
      }
    }
}

// ---------------------------------------------------------------------------
// Kernel 2: transpose V per head: [bh][t][d] -> [bh][d][t]
// ---------------------------------------------------------------------------
__global__ __launch_bounds__(256) void transpose_v_kernel(const bf16* __restrict__ vin,
                                                          bf16* __restrict__ vout) {
  __shared__ bf16 tile[64][72];
  const int bh = blockIdx.x;
  const int t0 = blockIdx.y * 64;
  const int tid = threadIdx.x;
  const int row = tid >> 2, cg = (tid & 3) * 16;
  const bf16* src = vin + ((size_t)bh * 1024 + t0 + row) * 64 + cg;
#pragma unroll
  for (int i = 0; i < 2; ++i) {
    v8bf x = *(const v8bf*)(src + i * 8);
#pragma unroll
    for (int jj = 0; jj < 8; ++jj) tile[row][cg + i * 8 + jj] = x[jj];
  }
  __syncthreads();
  const int d = tid >> 2, tg = (tid & 3) * 16;
  bf16* dst = vout + ((size_t)bh * 64 + d) * 1024 + t0 + tg;
  v8bf o0, o1;
#pragma unroll
  for (int i = 0; i < 8; ++i) o0[i] = tile[tg + i][d];
#pragma unroll
  for (int i = 0; i < 8; ++i) o1[i] = tile[tg + 8 + i][d];
  *(v8bf*)dst = o0;
  *(v8bf*)(dst + 8) = o1;
}

// ---------------------------------------------------------------------------
// Kernel 3: flash-style attention v3 — NO online softmax (scores bounded).
// ---------------------------------------------------------------------------
#define KSTR 72    // Ksm row stride: 64 data + 8 pad
#define VSTR 136   // Vsm/Psm row stride: 128 data + 8 pad

__global__ __launch_bounds__(256, 2) void attn_kernel(const bf16* __restrict__ qh,
                                                      const bf16* __restrict__ kh,
                                                      const bf16* __restrict__ vT,
                                                      bf16* __restrict__ attn_out) {
  __shared__ bf16 Ksm[128 * KSTR];    // 18432 B
  __shared__ bf16 Vsm[64 * VSTR];     // 17408 B
  __shared__ bf16 Psm[128 * VSTR];    // 34816 B
  const int L = blockIdx.x;  // 0..1023
  const int bh = (L & 7) * 16 + ((L >> 3) & 15);
  const int t0 = (L >> 7) * 128;
  const int tid = threadIdx.x;
  const int w = tid >> 6, l = tid & 63, quad = l >> 4, lr = l & 15;
  const int qr0 = t0 + w * 32;

  const bf16* khead = kh + (size_t)bh * 1024 * 64;
  const bf16* vhead = vT + (size_t)bh * 64 * 1024;

  const size_t qbase = ((size_t)bh * 1024 + qr0 + lr) * 64 + quad * 8;
  const v8bf bq00 = *(const v8bf*)(qh + qbase);
  const v8bf bq01 = *(const v8bf*)(qh + qbase + 32);
  const v8bf bq10 = *(const v8bf*)(qh + qbase + 1024);
  const v8bf bq11 = *(const v8bf*)(qh + qbase + 1024 + 32);

  const int krow = tid >> 1, kd = (tid & 1) * 32;
  const int vrow = tid >> 2, vk = (tid & 3) * 32;
  const bf16* kg = khead + (size_t)krow * 64 + kd;
  const bf16* vg = vhead + (size_t)vrow * 1024 + vk;
  bf16* Kw = &Ksm[krow * KSTR + kd];
  bf16* Vw = &Vsm[vrow * VSTR + vk];
  bf16* Pw = &Psm[w * 32 * VSTR];

  v8bf kst[4], vst[4];
#pragma unroll
  for (int i = 0; i < 4; ++i) kst[i] = *(const v8bf*)(kg + i * 8);
#pragma unroll
  for (int i = 0; i < 4; ++i) vst[i] = *(const v8bf*)(vg + i * 8);

  float rsum0 = 0.0f, rsum1 = 0.0f;
  f32x4 oacc0[4] = {}, oacc1[4] = {};

  for (int c = 0; c < 8; ++c) {
    __syncthreads();
#pragma unroll
    for (int i = 0; i < 4; ++i) *(v8bf*)(Kw + i * 8) = kst[i];
#pragma unroll
    for (int i = 0; i < 4; ++i) *(v8bf*)(Vw + i * 8) = vst[i];
    __syncthreads();
    if (c < 7) {
      const bf16* kg2 = kg + (size_t)(c + 1) * 128 * 64;
      const bf16* vg2 = vg + (c + 1) * 128;
#pragma unroll
      for (int i = 0; i < 4; ++i) kst[i] = *(const v8bf*)(kg2 + i * 8);
#pragma unroll
      for (int i = 0; i < 4; ++i) vst[i] = *(const v8bf*)(vg2 + i * 8);
    }

#pragma unroll
    for (int kt = 0; kt < 8; ++kt) {
      const v8bf ak0 = *(const v8bf*)&Ksm[(kt * 16 + lr) * KSTR + quad * 8];
      const v8bf ak1 = *(const v8bf*)&Ksm[(kt * 16 + lr) * KSTR + 32 + quad * 8];
      f32x4 a = {};
      a = MFMA16(ak0, bq00, a);
      a = MFMA16(ak1, bq01, a);
      f32x4 b = {};
      b = MFMA16(ak0, bq10, b);
      b = MFMA16(ak1, bq11, b);
      v4bf pb0, pb1;
#pragma unroll
      for (int j = 0; j < 4; ++j) {
        const float p0 = __expf(a[j]);
        const float p1 = __expf(b[j]);
        rsum0 += p0;
        rsum1 += p1;
        pb0[j] = (bf16)p0;
        pb1[j] = (bf16)p1;
      }
      *(v4bf*)(Pw + lr * VSTR + kt * 16 + quad * 4) = pb0;
      *(v4bf*)(Pw + (16 + lr) * VSTR + kt * 16 + quad * 4) = pb1;
    }

#pragma unroll
    for (int ks = 0; ks < 4; ++ks) {
      const v8bf pa0 = *(const v8bf*)(Pw + lr * VSTR + ks * 32 + quad * 8);
      const v8bf pa1 = *(const v8bf*)(Pw + (16 + lr) * VSTR + ks * 32 + quad * 8);
#pragma unroll
      for (int dt = 0; dt < 4; ++dt) {
        const v8bf vb = *(const v8bf*)&Vsm[(dt * 16 + lr) * VSTR + ks * 32 + quad * 8];
        oacc0[dt] = MFMA16(pa0, vb, oacc0[dt]);
        oacc1[dt] = MFMA16(pa1, vb, oacc1[dt]);
      }
    }
  }

  rsum0 += __shfl_xor(rsum0, 16);
  rsum0 += __shfl_xor(rsum0, 32);
  rsum1 += __shfl_xor(rsum1, 16);
  rsum1 += __shfl_xor(rsum1, 32);
  const float inv0 = 1.0f / rsum0;
  const float inv1 = 1.0f / rsum1;
  const int b = bh >> 4, h = bh & 15;
#pragma unroll
  for (int j = 0; j < 4; ++j) {
    const float i0 = __shfl(inv0, quad * 4 + j);
    const float i1 = __shfl(inv1, quad * 4 + j);
    const int t0j = qr0 + quad * 4 + j;
#pragma unroll
    for (int dt = 0; dt < 4; ++dt) {
      attn_out[((size_t)(t0j * 8 + b)) * 1024 + h * 64 + dt * 16 + lr] =
          (bf16)(oacc0[dt][j] * i0);
      attn_out[((size_t)((t0j + 16) * 8 + b)) * 1024 + h * 64 + dt * 16 + lr] =
          (bf16)(oacc1[dt][j] * i1);
    }
  }
}

// ---------------------------------------------------------------------------
// Kernel 4: out projection, same core. Grid 128 = 4 n x 32 m.
// ---------------------------------------------------------------------------
__global__ __launch_bounds__(512, 2) void out_proj_kernel(const bf16* __restrict__ A,
                                                          const bf16* __restrict__ Wob,
                                                          const float* __restrict__ bias,
                                                          float* __restrict__ out) {
  __shared__ bf16 Asm2[2][TSZ];
  __shared__ bf16 Bsm2[2][TSZ];
  bf16* Asmb = &Asm2[0][0];
  bf16* Bsmb = &Bsm2[0][0];
  const int L = blockIdx.x;  // 0..127
  const int n0 = (L >> 5) * 256;
  const int m0 = (L & 31) * 256;
  const bf16* Xa = A + (size_t)m0 * 1024;
  const bf16* Wbase = Wob + (size_t)n0 * 1024;

  GEMM_PRELUDE();

#pragma unroll
  for (int mf = 0; mf < 8; ++mf)
#pragma unroll
    for (int nf = 0; nf < 4; ++nf) {
      const int n = n0 + wng * 64 + nf * 16 + lr;
      const float bn = bias[n];
#pragma unroll
      for (int j = 0; j < 4; ++j) {
        const int m = m0 + wmg * 128 + (mf >> 2) * 64 + (mf & 3) * 16 +
                      quad * 4 + j;
        out[(size_t)m * 1024 + n] = acc[mf][nf][j] + bn;
      }
    }
}

// ---------------------------------------------------------------------------
// Launcher. Workspace (72 MB) + d_out as early scratch.
// ---------------------------------------------------------------------------
extern "C" void kernel_launch(void* const* d_in, const int* in_sizes, int n_in,
                              void* d_out, int out_size, void* d_ws, size_t ws_size,
                              hipStream_t stream) {
  const float* q  = (const float*)d_in[0];
  const float* k  = (const float*)d_in[1];
  const float* v  = (const float*)d_in[2];
  const float* wi = (const float*)d_in[3];
  const float* bi = (const float*)d_in[4];
  const float* wo = (const float*)d_in[5];
  const float* bo = (const float*)d_in[6];
  float* out = (float*)d_out;
  char* ws = (char*)d_ws;
  const size_t MB = (size_t)1 << 20;
  bf16* Wb     = (bf16*)(ws + 0 * MB);
  bf16* Wob    = (bf16*)(ws + 6 * MB);
  bf16* wsq    = (bf16*)(ws + 8 * MB);
  bf16* wsk    = (bf16*)(ws + 24 * MB);
  bf16* wsv    = (bf16*)(ws + 40 * MB);
  bf16* xv     = (bf16*)(ws + 56 * MB);
  bf16* wsvT   = (bf16*)(ws + 56 * MB);
  bf16* xq     = (bf16*)d_out;
  bf16* xk     = (bf16*)((char*)d_out + 16 * MB);
  bf16* wsattn = wsv;

  cvt_kernel<<<dim3(28672), dim3(256), 0, stream>>>(q, k, v, wi, wo, xq, xk, xv, Wb, Wob);
  qkv_proj_kernel<<<dim3(384), dim3(512), 0, stream>>>(xq, xk, xv, Wb, bi, wsq, wsk, wsv);
  transpose_v_kernel<<<dim3(128, 16), dim3(256), 0, stream>>>(wsv, wsvT);
  attn_kernel<<<dim3(1024), dim3(256), 0, stream>>>(wsq, wsk, wsvT, wsattn);
  out_proj_kernel<<<dim3(128), dim3(512), 0, stream>>>(wsattn, Wob, bo, out);
}